// Round 3
// baseline (46410.217 us; speedup 1.0000x reference)
//
#include <hip/hip_runtime.h>

// ---------------- common ----------------
typedef __bf16 bf16x8 __attribute__((ext_vector_type(8)));
typedef float f32x16 __attribute__((ext_vector_type(16)));
typedef unsigned int uint4v __attribute__((ext_vector_type(4)));

// ---- bf16 pack (RNE). EXACT round-0 harness-proven implementation.
#if __has_builtin(__builtin_amdgcn_cvt_pk_bf16_f32)
__device__ __forceinline__ unsigned packbf(float lo, float hi) {
    return __builtin_bit_cast(unsigned, __builtin_amdgcn_cvt_pk_bf16_f32(lo, hi));
}
#else
__device__ __forceinline__ unsigned rne_(float f) {
    unsigned u = __float_as_uint(f);
    return u + 0x7fffu + ((u >> 16) & 1u);
}
__device__ __forceinline__ unsigned packbf(float lo, float hi) {
    // result bytes: [lo.b2, lo.b3, hi.b2, hi.b3]
    return __builtin_amdgcn_perm(rne_(hi), rne_(lo), 0x07060302u);
}
#endif

__device__ __forceinline__ int ldf(const int* p) {
    return __hip_atomic_load(p, __ATOMIC_RELAXED, __HIP_MEMORY_SCOPE_WORKGROUP);
}
__device__ __forceinline__ void stf(int* p, int v) {
    __hip_atomic_store(p, v, __ATOMIC_RELAXED, __HIP_MEMORY_SCOPE_WORKGROUP);
}

#define SPIN_CAP (1 << 20)   // deadlock -> bounded wrong-answer run (diagnosable)

// ---------------- stage 1: chunked affine-scan ----------------
// u <- u*M_t + B2 is affine; chunk of 64 steps = pair (A, c), u_out = u_in*A + c,
// (A1,c1)o(A2,c2) = (A1A2, c1A2+c2).  Transposed so state stays the MFMA
// B-operand (kappa trick, layout verified):
//   A^T <- M_t^T A^T        (C-operand = 0)
//   c^T <- M_t^T c^T + B2^T (C-operand = cb2)
// init (I, 0).  8 chunks/batch -> 1024 independent blocks, critical path 64.
// NO s_setprio: a prio-1 wave spinning on a flag a prio-0 producer must set is
// a starvation deadlock hazard (prime suspect for rounds 1-2 hang).
#define CHUNK 64
#define NCH   8
#define NP1   3     // producer waves per block
#define S1    16    // ring slots (32 KB LDS)

__global__ void __launch_bounds__(64 * (NP1 + 1), 2)
minrnn_stage1(const float* __restrict__ x, const float* __restrict__ bvec,
              const float* __restrict__ b2vec,
              float* __restrict__ wsA, float* __restrict__ wsC)
{
    __shared__ unsigned ring[S1 * 512];   // slot base (t%S1)*512, elem d*64+l
    __shared__ int flags[S1];
    __shared__ int consumed;

    const int tid  = threadIdx.x;
    const int wave = tid >> 6;
    const int l    = tid & 63;
    const int col  = l & 31;
    const int half = l >> 5;
    const int bb   = blockIdx.x >> 3;     // batch
    const int ch   = blockIdx.x & 7;      // chunk

    if (tid < S1) flags[tid] = 0;
    if (tid == 0) consumed = -1;
    __syncthreads();

    if (wave == 0) {
        // ---------------- consumer: pair recurrence ----------------
        float uA[16], uC[16];
        f32x16 cb2, zc;
#pragma unroll
        for (int i = 0; i < 16; ++i) {
            const int row = (i & 3) + 8 * (i >> 2) + 4 * half;
            cb2[i] = b2vec[col * 32 + row];
            zc[i]  = 0.f;
            uA[i]  = (row == col) ? 1.f : 0.f;   // identity (exact in bf16)
            uC[i]  = 0.f;
        }

        int flagn = ldf(&flags[0]);
        {
            int g = 0;
            while (flagn != 1 && ++g < SPIN_CAP) flagn = ldf(&flags[0]);
        }
        __threadfence_block();
        unsigned cur[8], nxt[8];
#pragma unroll
        for (int d = 0; d < 8; ++d) cur[d] = ring[d * 64 + l];
        flagn = ldf(&flags[1]);

        for (int t = 0; t < CHUNK; ++t) {
            if (t < CHUNK - 1) {
                const int want = t + 2;
                int g = 0;
                while (flagn != want && ++g < SPIN_CAP)
                    flagn = ldf(&flags[(t + 1) & (S1 - 1)]);
                __threadfence_block();
                const int sb = ((t + 1) & (S1 - 1)) << 9;
#pragma unroll
                for (int d = 0; d < 8; ++d) nxt[d] = ring[sb + d * 64 + l];
                if (t + 2 < CHUNK) flagn = ldf(&flags[(t + 2) & (S1 - 1)]);
            }

            unsigned pA[8], pC[8];
#pragma unroll
            for (int i = 0; i < 8; ++i) {
                pA[i] = packbf(uA[2 * i], uA[2 * i + 1]);
                pC[i] = packbf(uC[2 * i], uC[2 * i + 1]);
            }
            const bf16x8 A0  = __builtin_bit_cast(bf16x8, (uint4v){cur[0], cur[1], cur[2], cur[3]});
            const bf16x8 A1  = __builtin_bit_cast(bf16x8, (uint4v){cur[4], cur[5], cur[6], cur[7]});
            const bf16x8 BA0 = __builtin_bit_cast(bf16x8, (uint4v){pA[0], pA[1], pA[2], pA[3]});
            const bf16x8 BA1 = __builtin_bit_cast(bf16x8, (uint4v){pA[4], pA[5], pA[6], pA[7]});
            const bf16x8 BC0 = __builtin_bit_cast(bf16x8, (uint4v){pC[0], pC[1], pC[2], pC[3]});
            const bf16x8 BC1 = __builtin_bit_cast(bf16x8, (uint4v){pC[4], pC[5], pC[6], pC[7]});

            // two independent 2-MFMA chains (A-state, c-state) fill the pipe
            f32x16 accA = __builtin_amdgcn_mfma_f32_32x32x16_bf16(A0, BA0, zc, 0, 0, 0);
            f32x16 accC = __builtin_amdgcn_mfma_f32_32x32x16_bf16(A0, BC0, cb2, 0, 0, 0);
            accA        = __builtin_amdgcn_mfma_f32_32x32x16_bf16(A1, BA1, accA, 0, 0, 0);
            accC        = __builtin_amdgcn_mfma_f32_32x32x16_bf16(A1, BC1, accC, 0, 0, 0);
#pragma unroll
            for (int i = 0; i < 16; ++i) { uA[i] = accA[i]; uC[i] = accC[i]; }

            if (l == 0 && (t & 7) == 7) stf(&consumed, t);
#pragma unroll
            for (int d = 0; d < 8; ++d) cur[d] = nxt[d];
        }

        // store pair row-major f32: ws[r*32+c] = X^T[r][c] (coalesced per reg)
        const size_t base = (size_t)blockIdx.x * 1024;
#pragma unroll
        for (int i = 0; i < 16; ++i) {
            const int row = (i & 3) + 8 * (i >> 2) + 4 * half;
            wsA[base + row * 32 + col] = uA[i];
            wsC[base + row * 32 + col] = uC[i];
        }
    } else {
        // ---------------- producers (round-0 proven structure) ----------------
        const int p = wave - 1;
        float bA[16];
        int off[16];
#pragma unroll
        for (int c = 0; c < 2; ++c)
#pragma unroll
            for (int j = 0; j < 8; ++j) {
                const int k = c * 16 + half * 4 + (j & 3) + 8 * (j >> 2); // kappa
                bA[c * 8 + j]  = bvec[k * 32 + col];
                off[c * 8 + j] = c * 512 + half * 128 + (j >> 2) * 256 + (j & 3) * 32 + col;
            }
        const float* xb = x + ((size_t)bb * 512 + ch * CHUNK) * 1024;

        auto emit = [&](int t, const float* v) {
            int g = 0;
            while (ldf(&consumed) < t - (S1 + 1) && ++g < SPIN_CAP) {}
            unsigned pa[8];
#pragma unroll
            for (int i = 0; i < 8; ++i)
                pa[i] = packbf(v[2 * i] + bA[2 * i], v[2 * i + 1] + bA[2 * i + 1]);
            const int sb = (t & (S1 - 1)) << 9;
#pragma unroll
            for (int d = 0; d < 8; ++d) ring[sb + d * 64 + l] = pa[d];
            __threadfence_block();
            if (l == 0) stf(&flags[t & (S1 - 1)], t + 1);
        };

        for (int t = p; t < CHUNK; t += 2 * NP1) {
            const int t2 = t + NP1;
            float va[16], vb[16];
#pragma unroll
            for (int i = 0; i < 16; ++i) va[i] = xb[t * 1024 + off[i]];
            if (t2 < CHUNK) {
#pragma unroll
                for (int i = 0; i < 16; ++i) vb[i] = xb[t2 * 1024 + off[i]];
            }
            __builtin_amdgcn_sched_barrier(0);
            emit(t, va);
            if (t2 < CHUNK) emit(t2, vb);
        }
    }
}

// ---------------- stage 2: compose 8 chunk pairs per batch ----------------
// u^T <- A_j^T u^T + c_j^T, j = 0..7; state stays the B-operand (C/D layout).
// A-frag layout (derived from proven producer): frag(lane(half,col), e=(c,j))
// = A_seen[col][kappa]; ws holds A_ch^T row-major -> gather ws[col*32+kappa].
__global__ void __launch_bounds__(64, 1)
minrnn_stage2(const float* __restrict__ wsA, const float* __restrict__ wsC,
              const float* __restrict__ b2vec, const float* __restrict__ h0,
              float* __restrict__ out)
{
    const int l = threadIdx.x, col = l & 31, half = l >> 5, bb = blockIdx.x;
    float u[16];
    f32x16 cb2;
    int offA[16], offC[16];
#pragma unroll
    for (int i = 0; i < 16; ++i) {
        const int row = (i & 3) + 8 * (i >> 2) + 4 * half;
        cb2[i]  = b2vec[col * 32 + row];
        u[i]    = h0[bb * 1024 + col * 32 + row] + cb2[i];   // u0 = B2 + h0
        offC[i] = row * 32 + col;
    }
#pragma unroll
    for (int c = 0; c < 2; ++c)
#pragma unroll
        for (int j = 0; j < 8; ++j) {
            const int k = c * 16 + half * 4 + (j & 3) + 8 * (j >> 2);   // kappa
            offA[c * 8 + j] = col * 32 + k;
        }

    const float* bA = wsA + (size_t)bb * NCH * 1024;
    const float* bC = wsC + (size_t)bb * NCH * 1024;

    float av[2][16], cv[2][16];
#pragma unroll
    for (int i = 0; i < 16; ++i) { av[0][i] = bA[offA[i]]; cv[0][i] = bC[offC[i]]; }

#pragma unroll
    for (int j = 0; j < 8; ++j) {
        const int cb = j & 1, nb = cb ^ 1;
        if (j < 7) {
#pragma unroll
            for (int i = 0; i < 16; ++i) {
                av[nb][i] = bA[(j + 1) * 1024 + offA[i]];
                cv[nb][i] = bC[(j + 1) * 1024 + offC[i]];
            }
        }
        unsigned pu[8], pa[8];
#pragma unroll
        for (int i = 0; i < 8; ++i) {
            pu[i] = packbf(u[2 * i], u[2 * i + 1]);
            pa[i] = packbf(av[cb][2 * i], av[cb][2 * i + 1]);
        }
        const bf16x8 A0 = __builtin_bit_cast(bf16x8, (uint4v){pa[0], pa[1], pa[2], pa[3]});
        const bf16x8 A1 = __builtin_bit_cast(bf16x8, (uint4v){pa[4], pa[5], pa[6], pa[7]});
        const bf16x8 B0 = __builtin_bit_cast(bf16x8, (uint4v){pu[0], pu[1], pu[2], pu[3]});
        const bf16x8 B1 = __builtin_bit_cast(bf16x8, (uint4v){pu[4], pu[5], pu[6], pu[7]});
        f32x16 cc;
#pragma unroll
        for (int i = 0; i < 16; ++i) cc[i] = cv[cb][i];
        f32x16 acc = __builtin_amdgcn_mfma_f32_32x32x16_bf16(A0, B0, cc, 0, 0, 0);
        acc        = __builtin_amdgcn_mfma_f32_32x32x16_bf16(A1, B1, acc, 0, 0, 0);
#pragma unroll
        for (int i = 0; i < 16; ++i) u[i] = acc[i];
    }

#pragma unroll
    for (int i = 0; i < 16; ++i) {
        const int row = (i & 3) + 8 * (i >> 2) + 4 * half;
        out[bb * 1024 + col * 32 + row] = u[i] - cb2[i];
    }
}

// ---------------- fallback: round-0 verified single-kernel path ----------------
#define TSTEPS 512
#define NPF 7
#define SF  32

__global__ void __launch_bounds__(64 * (NPF + 1), 1)
minrnn_fallback(const float* __restrict__ x, const float* __restrict__ bvec,
                const float* __restrict__ b2vec, const float* __restrict__ h0,
                float* __restrict__ out)
{
    __shared__ unsigned ring[SF * 512];
    __shared__ int flags[SF];
    __shared__ int consumed;

    const int tid  = threadIdx.x;
    const int wave = tid >> 6;
    const int l    = tid & 63;
    const int col  = l & 31;
    const int half = l >> 5;
    const int bb   = blockIdx.x;

    if (tid < SF) flags[tid] = 0;
    if (tid == 0) consumed = -1;
    __syncthreads();

    if (wave == 0) {
        float u[16];
        f32x16 cb2;
#pragma unroll
        for (int i = 0; i < 16; ++i) {
            const int row = (i & 3) + 8 * (i >> 2) + 4 * half;
            const float b2v = b2vec[col * 32 + row];
            cb2[i] = b2v;
            u[i] = h0[bb * 1024 + col * 32 + row] + b2v;
        }
        int flagn = ldf(&flags[0]);
        while (flagn != 1) flagn = ldf(&flags[0]);
        __threadfence_block();
        unsigned cur[8], nxt[8];
#pragma unroll
        for (int d = 0; d < 8; ++d) cur[d] = ring[d * 64 + l];
        flagn = ldf(&flags[1]);

        for (int t = 0; t < TSTEPS; ++t) {
            if (t < TSTEPS - 1) {
                const int want = t + 2;
                while (flagn != want) flagn = ldf(&flags[(t + 1) & (SF - 1)]);
                __threadfence_block();
                const int sb = ((t + 1) & (SF - 1)) << 9;
#pragma unroll
                for (int d = 0; d < 8; ++d) nxt[d] = ring[sb + d * 64 + l];
                if (t + 2 < TSTEPS) flagn = ldf(&flags[(t + 2) & (SF - 1)]);
            }
            unsigned pb[8];
#pragma unroll
            for (int i = 0; i < 8; ++i) pb[i] = packbf(u[2 * i], u[2 * i + 1]);
            const bf16x8 B0 = __builtin_bit_cast(bf16x8, (uint4v){pb[0], pb[1], pb[2], pb[3]});
            const bf16x8 B1 = __builtin_bit_cast(bf16x8, (uint4v){pb[4], pb[5], pb[6], pb[7]});
            const bf16x8 A0 = __builtin_bit_cast(bf16x8, (uint4v){cur[0], cur[1], cur[2], cur[3]});
            const bf16x8 A1 = __builtin_bit_cast(bf16x8, (uint4v){cur[4], cur[5], cur[6], cur[7]});

            f32x16 acc = __builtin_amdgcn_mfma_f32_32x32x16_bf16(A0, B0, cb2, 0, 0, 0);
            acc        = __builtin_amdgcn_mfma_f32_32x32x16_bf16(A1, B1, acc, 0, 0, 0);
#pragma unroll
            for (int i = 0; i < 16; ++i) u[i] = acc[i];

            if (l == 0 && (t & 7) == 7) stf(&consumed, t);
#pragma unroll
            for (int d = 0; d < 8; ++d) cur[d] = nxt[d];
        }
#pragma unroll
        for (int i = 0; i < 16; ++i) {
            const int row = (i & 3) + 8 * (i >> 2) + 4 * half;
            out[bb * 1024 + col * 32 + row] = u[i] - cb2[i];
        }
    } else {
        const int p = wave - 1;
        float bA[16];
        int off[16];
#pragma unroll
        for (int c = 0; c < 2; ++c)
#pragma unroll
            for (int j = 0; j < 8; ++j) {
                const int k = c * 16 + half * 4 + (j & 3) + 8 * (j >> 2);
                bA[c * 8 + j]  = bvec[k * 32 + col];
                off[c * 8 + j] = c * 512 + half * 128 + (j >> 2) * 256 + (j & 3) * 32 + col;
            }
        const float* xb = x + (size_t)bb * TSTEPS * 1024;

        auto emit = [&](int t, const float* v) {
            while (ldf(&consumed) < t - (SF + 1)) {}
            unsigned pa[8];
#pragma unroll
            for (int i = 0; i < 8; ++i)
                pa[i] = packbf(v[2 * i] + bA[2 * i], v[2 * i + 1] + bA[2 * i + 1]);
            const int sb = (t & (SF - 1)) << 9;
#pragma unroll
            for (int d = 0; d < 8; ++d) ring[sb + d * 64 + l] = pa[d];
            __threadfence_block();
            if (l == 0) stf(&flags[t & (SF - 1)], t + 1);
        };

        for (int t = p; t < TSTEPS; t += 2 * NPF) {
            const int t2 = t + NPF;
            float va[16], vb[16];
#pragma unroll
            for (int i = 0; i < 16; ++i) va[i] = xb[t * 1024 + off[i]];
            if (t2 < TSTEPS) {
#pragma unroll
                for (int i = 0; i < 16; ++i) vb[i] = xb[t2 * 1024 + off[i]];
            }
            __builtin_amdgcn_sched_barrier(0);
            emit(t, va);
            if (t2 < TSTEPS) emit(t2, vb);
        }
    }
}

extern "C" void kernel_launch(void* const* d_in, const int* in_sizes, int n_in,
                              void* d_out, int out_size, void* d_ws, size_t ws_size,
                              hipStream_t stream)
{
    const float* x  = (const float*)d_in[0];
    const float* b  = (const float*)d_in[1];
    const float* b2 = (const float*)d_in[2];
    const float* h0 = (const float*)d_in[3];
    float* out = (float*)d_out;

    const size_t need = (size_t)128 * NCH * 1024 * sizeof(float) * 2;  // 8 MB
    if (d_ws && ws_size >= need) {
        float* wsA = (float*)d_ws;
        float* wsC = wsA + (size_t)128 * NCH * 1024;
        minrnn_stage1<<<128 * NCH, 64 * (NP1 + 1), 0, stream>>>(x, b, b2, wsA, wsC);
        minrnn_stage2<<<128, 64, 0, stream>>>(wsA, wsC, b2, h0, out);
    } else {
        minrnn_fallback<<<128, 64 * (NPF + 1), 0, stream>>>(x, b, b2, h0, out);
    }
}

// Round 4
// 374.691 us; speedup vs baseline: 123.8625x; 123.8625x over previous
//
#include <hip/hip_runtime.h>

// ---------------- common ----------------
typedef __bf16 bf16x8 __attribute__((ext_vector_type(8)));
typedef float f32x16 __attribute__((ext_vector_type(16)));
typedef unsigned int uint4v __attribute__((ext_vector_type(4)));

// ---- bf16 pack (RNE). EXACT round-0 harness-proven implementation.
#if __has_builtin(__builtin_amdgcn_cvt_pk_bf16_f32)
__device__ __forceinline__ unsigned packbf(float lo, float hi) {
    return __builtin_bit_cast(unsigned, __builtin_amdgcn_cvt_pk_bf16_f32(lo, hi));
}
#else
__device__ __forceinline__ unsigned rne_(float f) {
    unsigned u = __float_as_uint(f);
    return u + 0x7fffu + ((u >> 16) & 1u);
}
__device__ __forceinline__ unsigned packbf(float lo, float hi) {
    // result bytes: [lo.b2, lo.b3, hi.b2, hi.b3]
    return __builtin_amdgcn_perm(rne_(hi), rne_(lo), 0x07060302u);
}
#endif

__device__ __forceinline__ int ldf(const int* p) {
    return __hip_atomic_load(p, __ATOMIC_RELAXED, __HIP_MEMORY_SCOPE_WORKGROUP);
}
__device__ __forceinline__ void stf(int* p, int v) {
    __hip_atomic_store(p, v, __ATOMIC_RELAXED, __HIP_MEMORY_SCOPE_WORKGROUP);
}

// ---------------- stage 1: chunked affine-scan ----------------
// u <- u*M_t + B2 is affine; chunk of 64 steps = pair (A, c), u_out = u_in*A + c,
// (A1,c1)o(A2,c2) = (A1A2, c1A2+c2).  Transposed so state stays the MFMA
// B-operand (kappa trick, layout verified by round-3 PASS, absmax 2.44e-4):
//   A^T <- M_t^T A^T        (C-operand = 0)
//   c^T <- M_t^T c^T + B2^T (C-operand = cb2)
// init (I, 0).  8 chunks/batch -> 1024 independent blocks, critical path 64.
//
// ROUND-4 REVERT: round-3's spin-cap counters + __launch_bounds__(256,2)
// produced a 52-VGPR scratch-spilled build (rocprof) -> 1000x slowdown on the
// chain. This version is byte-for-byte the ROUND-0 PROVEN geometry (NP=7,
// S=32, LB(512,1), unbounded relaxed-atomic spins, no setprio, no caps) with
// only the affine-scan deltas: dual chain, CHUNK=64 bounds, ws epilogue.
#define CHUNK 64
#define NCH   8
#define NP1   7     // producer waves per block (round-0 proven)
#define S1    32    // ring slots (64 KB LDS, round-0 proven)

__global__ void __launch_bounds__(64 * (NP1 + 1), 1)
minrnn_stage1(const float* __restrict__ x, const float* __restrict__ bvec,
              const float* __restrict__ b2vec,
              float* __restrict__ wsA, float* __restrict__ wsC)
{
    __shared__ unsigned ring[S1 * 512];   // slot base (t%S1)*512, elem d*64+l
    __shared__ int flags[S1];
    __shared__ int consumed;

    const int tid  = threadIdx.x;
    const int wave = tid >> 6;
    const int l    = tid & 63;
    const int col  = l & 31;
    const int half = l >> 5;
    const int bb   = blockIdx.x >> 3;     // batch
    const int ch   = blockIdx.x & 7;      // chunk

    if (tid < S1) flags[tid] = 0;
    if (tid == 0) consumed = -1;
    __syncthreads();

    if (wave == 0) {
        // ---------------- consumer: pair recurrence ----------------
        float uA[16], uC[16];
        f32x16 cb2, zc;
#pragma unroll
        for (int i = 0; i < 16; ++i) {
            const int row = (i & 3) + 8 * (i >> 2) + 4 * half;
            cb2[i] = b2vec[col * 32 + row];
            zc[i]  = 0.f;
            uA[i]  = (row == col) ? 1.f : 0.f;   // identity (exact in bf16)
            uC[i]  = 0.f;
        }

        int flagn = ldf(&flags[0]);
        while (flagn != 1) flagn = ldf(&flags[0]);
        __threadfence_block();
        unsigned cur[8], nxt[8];
#pragma unroll
        for (int d = 0; d < 8; ++d) cur[d] = ring[d * 64 + l];
        flagn = ldf(&flags[1]);

        for (int t = 0; t < CHUNK; ++t) {
            if (t < CHUNK - 1) {
                const int want = t + 2;
                while (flagn != want) flagn = ldf(&flags[(t + 1) & (S1 - 1)]);
                __threadfence_block();
                const int sb = ((t + 1) & (S1 - 1)) << 9;
#pragma unroll
                for (int d = 0; d < 8; ++d) nxt[d] = ring[sb + d * 64 + l];
                if (t + 2 < CHUNK) flagn = ldf(&flags[(t + 2) & (S1 - 1)]);
            }

            unsigned pA[8], pC[8];
#pragma unroll
            for (int i = 0; i < 8; ++i) {
                pA[i] = packbf(uA[2 * i], uA[2 * i + 1]);
                pC[i] = packbf(uC[2 * i], uC[2 * i + 1]);
            }
            const bf16x8 A0  = __builtin_bit_cast(bf16x8, (uint4v){cur[0], cur[1], cur[2], cur[3]});
            const bf16x8 A1  = __builtin_bit_cast(bf16x8, (uint4v){cur[4], cur[5], cur[6], cur[7]});
            const bf16x8 BA0 = __builtin_bit_cast(bf16x8, (uint4v){pA[0], pA[1], pA[2], pA[3]});
            const bf16x8 BA1 = __builtin_bit_cast(bf16x8, (uint4v){pA[4], pA[5], pA[6], pA[7]});
            const bf16x8 BC0 = __builtin_bit_cast(bf16x8, (uint4v){pC[0], pC[1], pC[2], pC[3]});
            const bf16x8 BC1 = __builtin_bit_cast(bf16x8, (uint4v){pC[4], pC[5], pC[6], pC[7]});

            // two independent 2-MFMA chains (A-state, c-state) fill the pipe
            f32x16 accA = __builtin_amdgcn_mfma_f32_32x32x16_bf16(A0, BA0, zc, 0, 0, 0);
            f32x16 accC = __builtin_amdgcn_mfma_f32_32x32x16_bf16(A0, BC0, cb2, 0, 0, 0);
            accA        = __builtin_amdgcn_mfma_f32_32x32x16_bf16(A1, BA1, accA, 0, 0, 0);
            accC        = __builtin_amdgcn_mfma_f32_32x32x16_bf16(A1, BC1, accC, 0, 0, 0);
#pragma unroll
            for (int i = 0; i < 16; ++i) { uA[i] = accA[i]; uC[i] = accC[i]; }

            if (l == 0 && (t & 7) == 7) stf(&consumed, t);
#pragma unroll
            for (int d = 0; d < 8; ++d) cur[d] = nxt[d];
        }

        // store pair row-major f32: ws[r*32+c] = X^T[r][c] (coalesced per reg)
        const size_t base = (size_t)blockIdx.x * 1024;
#pragma unroll
        for (int i = 0; i < 16; ++i) {
            const int row = (i & 3) + 8 * (i >> 2) + 4 * half;
            wsA[base + row * 32 + col] = uA[i];
            wsC[base + row * 32 + col] = uC[i];
        }
    } else {
        // ---------------- producers (round-0 proven structure) ----------------
        const int p = wave - 1;
        float bA[16];
        int off[16];
#pragma unroll
        for (int c = 0; c < 2; ++c)
#pragma unroll
            for (int j = 0; j < 8; ++j) {
                const int k = c * 16 + half * 4 + (j & 3) + 8 * (j >> 2); // kappa
                bA[c * 8 + j]  = bvec[k * 32 + col];
                off[c * 8 + j] = c * 512 + half * 128 + (j >> 2) * 256 + (j & 3) * 32 + col;
            }
        const float* xb = x + ((size_t)bb * 512 + ch * CHUNK) * 1024;

        auto emit = [&](int t, const float* v) {
            while (ldf(&consumed) < t - (S1 + 1)) {}
            unsigned pa[8];
#pragma unroll
            for (int i = 0; i < 8; ++i)
                pa[i] = packbf(v[2 * i] + bA[2 * i], v[2 * i + 1] + bA[2 * i + 1]);
            const int sb = (t & (S1 - 1)) << 9;
#pragma unroll
            for (int d = 0; d < 8; ++d) ring[sb + d * 64 + l] = pa[d];
            __threadfence_block();
            if (l == 0) stf(&flags[t & (S1 - 1)], t + 1);
        };

        for (int t = p; t < CHUNK; t += 2 * NP1) {
            const int t2 = t + NP1;
            float va[16], vb[16];
#pragma unroll
            for (int i = 0; i < 16; ++i) va[i] = xb[t * 1024 + off[i]];
            if (t2 < CHUNK) {
#pragma unroll
                for (int i = 0; i < 16; ++i) vb[i] = xb[t2 * 1024 + off[i]];
            }
            __builtin_amdgcn_sched_barrier(0);
            emit(t, va);
            if (t2 < CHUNK) emit(t2, vb);
        }
    }
}

// ---------------- stage 2: compose 8 chunk pairs per batch ----------------
// (verified round 3, absmax 2.44e-4 — unchanged)
// u^T <- A_j^T u^T + c_j^T, j = 0..7; state stays the B-operand (C/D layout).
// A-frag layout (derived from proven producer): frag(lane(half,col), e=(c,j))
// = A_seen[col][kappa]; ws holds A_ch^T row-major -> gather ws[col*32+kappa].
__global__ void __launch_bounds__(64, 1)
minrnn_stage2(const float* __restrict__ wsA, const float* __restrict__ wsC,
              const float* __restrict__ b2vec, const float* __restrict__ h0,
              float* __restrict__ out)
{
    const int l = threadIdx.x, col = l & 31, half = l >> 5, bb = blockIdx.x;
    float u[16];
    f32x16 cb2;
    int offA[16], offC[16];
#pragma unroll
    for (int i = 0; i < 16; ++i) {
        const int row = (i & 3) + 8 * (i >> 2) + 4 * half;
        cb2[i]  = b2vec[col * 32 + row];
        u[i]    = h0[bb * 1024 + col * 32 + row] + cb2[i];   // u0 = B2 + h0
        offC[i] = row * 32 + col;
    }
#pragma unroll
    for (int c = 0; c < 2; ++c)
#pragma unroll
        for (int j = 0; j < 8; ++j) {
            const int k = c * 16 + half * 4 + (j & 3) + 8 * (j >> 2);   // kappa
            offA[c * 8 + j] = col * 32 + k;
        }

    const float* bA = wsA + (size_t)bb * NCH * 1024;
    const float* bC = wsC + (size_t)bb * NCH * 1024;

    float av[2][16], cv[2][16];
#pragma unroll
    for (int i = 0; i < 16; ++i) { av[0][i] = bA[offA[i]]; cv[0][i] = bC[offC[i]]; }

#pragma unroll
    for (int j = 0; j < 8; ++j) {
        const int cb = j & 1, nb = cb ^ 1;
        if (j < 7) {
#pragma unroll
            for (int i = 0; i < 16; ++i) {
                av[nb][i] = bA[(j + 1) * 1024 + offA[i]];
                cv[nb][i] = bC[(j + 1) * 1024 + offC[i]];
            }
        }
        unsigned pu[8], pa[8];
#pragma unroll
        for (int i = 0; i < 8; ++i) {
            pu[i] = packbf(u[2 * i], u[2 * i + 1]);
            pa[i] = packbf(av[cb][2 * i], av[cb][2 * i + 1]);
        }
        const bf16x8 A0 = __builtin_bit_cast(bf16x8, (uint4v){pa[0], pa[1], pa[2], pa[3]});
        const bf16x8 A1 = __builtin_bit_cast(bf16x8, (uint4v){pa[4], pa[5], pa[6], pa[7]});
        const bf16x8 B0 = __builtin_bit_cast(bf16x8, (uint4v){pu[0], pu[1], pu[2], pu[3]});
        const bf16x8 B1 = __builtin_bit_cast(bf16x8, (uint4v){pu[4], pu[5], pu[6], pu[7]});
        f32x16 cc;
#pragma unroll
        for (int i = 0; i < 16; ++i) cc[i] = cv[cb][i];
        f32x16 acc = __builtin_amdgcn_mfma_f32_32x32x16_bf16(A0, B0, cc, 0, 0, 0);
        acc        = __builtin_amdgcn_mfma_f32_32x32x16_bf16(A1, B1, acc, 0, 0, 0);
#pragma unroll
        for (int i = 0; i < 16; ++i) u[i] = acc[i];
    }

#pragma unroll
    for (int i = 0; i < 16; ++i) {
        const int row = (i & 3) + 8 * (i >> 2) + 4 * half;
        out[bb * 1024 + col * 32 + row] = u[i] - cb2[i];
    }
}

// ---------------- fallback: round-0 verified single-kernel path ----------------
#define TSTEPS 512
#define NPF 7
#define SF  32

__global__ void __launch_bounds__(64 * (NPF + 1), 1)
minrnn_fallback(const float* __restrict__ x, const float* __restrict__ bvec,
                const float* __restrict__ b2vec, const float* __restrict__ h0,
                float* __restrict__ out)
{
    __shared__ unsigned ring[SF * 512];
    __shared__ int flags[SF];
    __shared__ int consumed;

    const int tid  = threadIdx.x;
    const int wave = tid >> 6;
    const int l    = tid & 63;
    const int col  = l & 31;
    const int half = l >> 5;
    const int bb   = blockIdx.x;

    if (tid < SF) flags[tid] = 0;
    if (tid == 0) consumed = -1;
    __syncthreads();

    if (wave == 0) {
        float u[16];
        f32x16 cb2;
#pragma unroll
        for (int i = 0; i < 16; ++i) {
            const int row = (i & 3) + 8 * (i >> 2) + 4 * half;
            const float b2v = b2vec[col * 32 + row];
            cb2[i] = b2v;
            u[i] = h0[bb * 1024 + col * 32 + row] + b2v;
        }
        int flagn = ldf(&flags[0]);
        while (flagn != 1) flagn = ldf(&flags[0]);
        __threadfence_block();
        unsigned cur[8], nxt[8];
#pragma unroll
        for (int d = 0; d < 8; ++d) cur[d] = ring[d * 64 + l];
        flagn = ldf(&flags[1]);

        for (int t = 0; t < TSTEPS; ++t) {
            if (t < TSTEPS - 1) {
                const int want = t + 2;
                while (flagn != want) flagn = ldf(&flags[(t + 1) & (SF - 1)]);
                __threadfence_block();
                const int sb = ((t + 1) & (SF - 1)) << 9;
#pragma unroll
                for (int d = 0; d < 8; ++d) nxt[d] = ring[sb + d * 64 + l];
                if (t + 2 < TSTEPS) flagn = ldf(&flags[(t + 2) & (SF - 1)]);
            }
            unsigned pb[8];
#pragma unroll
            for (int i = 0; i < 8; ++i) pb[i] = packbf(u[2 * i], u[2 * i + 1]);
            const bf16x8 B0 = __builtin_bit_cast(bf16x8, (uint4v){pb[0], pb[1], pb[2], pb[3]});
            const bf16x8 B1 = __builtin_bit_cast(bf16x8, (uint4v){pb[4], pb[5], pb[6], pb[7]});
            const bf16x8 A0 = __builtin_bit_cast(bf16x8, (uint4v){cur[0], cur[1], cur[2], cur[3]});
            const bf16x8 A1 = __builtin_bit_cast(bf16x8, (uint4v){cur[4], cur[5], cur[6], cur[7]});

            f32x16 acc = __builtin_amdgcn_mfma_f32_32x32x16_bf16(A0, B0, cb2, 0, 0, 0);
            acc        = __builtin_amdgcn_mfma_f32_32x32x16_bf16(A1, B1, acc, 0, 0, 0);
#pragma unroll
            for (int i = 0; i < 16; ++i) u[i] = acc[i];

            if (l == 0 && (t & 7) == 7) stf(&consumed, t);
#pragma unroll
            for (int d = 0; d < 8; ++d) cur[d] = nxt[d];
        }
#pragma unroll
        for (int i = 0; i < 16; ++i) {
            const int row = (i & 3) + 8 * (i >> 2) + 4 * half;
            out[bb * 1024 + col * 32 + row] = u[i] - cb2[i];
        }
    } else {
        const int p = wave - 1;
        float bA[16];
        int off[16];
#pragma unroll
        for (int c = 0; c < 2; ++c)
#pragma unroll
            for (int j = 0; j < 8; ++j) {
                const int k = c * 16 + half * 4 + (j & 3) + 8 * (j >> 2);
                bA[c * 8 + j]  = bvec[k * 32 + col];
                off[c * 8 + j] = c * 512 + half * 128 + (j >> 2) * 256 + (j & 3) * 32 + col;
            }
        const float* xb = x + (size_t)bb * TSTEPS * 1024;

        auto emit = [&](int t, const float* v) {
            while (ldf(&consumed) < t - (SF + 1)) {}
            unsigned pa[8];
#pragma unroll
            for (int i = 0; i < 8; ++i)
                pa[i] = packbf(v[2 * i] + bA[2 * i], v[2 * i + 1] + bA[2 * i + 1]);
            const int sb = (t & (SF - 1)) << 9;
#pragma unroll
            for (int d = 0; d < 8; ++d) ring[sb + d * 64 + l] = pa[d];
            __threadfence_block();
            if (l == 0) stf(&flags[t & (SF - 1)], t + 1);
        };

        for (int t = p; t < TSTEPS; t += 2 * NPF) {
            const int t2 = t + NPF;
            float va[16], vb[16];
#pragma unroll
            for (int i = 0; i < 16; ++i) va[i] = xb[t * 1024 + off[i]];
            if (t2 < TSTEPS) {
#pragma unroll
                for (int i = 0; i < 16; ++i) vb[i] = xb[t2 * 1024 + off[i]];
            }
            __builtin_amdgcn_sched_barrier(0);
            emit(t, va);
            if (t2 < TSTEPS) emit(t2, vb);
        }
    }
}

extern "C" void kernel_launch(void* const* d_in, const int* in_sizes, int n_in,
                              void* d_out, int out_size, void* d_ws, size_t ws_size,
                              hipStream_t stream)
{
    const float* x  = (const float*)d_in[0];
    const float* b  = (const float*)d_in[1];
    const float* b2 = (const float*)d_in[2];
    const float* h0 = (const float*)d_in[3];
    float* out = (float*)d_out;

    const size_t need = (size_t)128 * NCH * 1024 * sizeof(float) * 2;  // 8 MB
    if (d_ws && ws_size >= need) {
        float* wsA = (float*)d_ws;
        float* wsC = wsA + (size_t)128 * NCH * 1024;
        minrnn_stage1<<<128 * NCH, 64 * (NP1 + 1), 0, stream>>>(x, b, b2, wsA, wsC);
        minrnn_stage2<<<128, 64, 0, stream>>>(wsA, wsC, b2, h0, out);
    } else {
        minrnn_fallback<<<128, 64 * (NPF + 1), 0, stream>>>(x, b, b2, h0, out);
    }
}

// Round 5
// 367.382 us; speedup vs baseline: 126.3268x; 1.0199x over previous
//
#include <hip/hip_runtime.h>

#define TSTEPS 512
#define NP 7            // producer waves per block
#define S  32           // ring slots (power of 2)

typedef __bf16 bf16x8 __attribute__((ext_vector_type(8)));
typedef float f32x16 __attribute__((ext_vector_type(16)));
typedef unsigned int uint4v __attribute__((ext_vector_type(4)));

// ---- bf16 pack (RNE). gfx950 has v_cvt_pk_bf16_f32; guarded fallback uses
// the add-round + v_perm_b32 byte-select trick (7 insts vs 1).
#if __has_builtin(__builtin_amdgcn_cvt_pk_bf16_f32)
__device__ __forceinline__ unsigned packbf(float lo, float hi) {
    return __builtin_bit_cast(unsigned, __builtin_amdgcn_cvt_pk_bf16_f32(lo, hi));
}
#else
__device__ __forceinline__ unsigned rne_(float f) {
    unsigned u = __float_as_uint(f);
    return u + 0x7fffu + ((u >> 16) & 1u);
}
__device__ __forceinline__ unsigned packbf(float lo, float hi) {
    // result bytes: [lo.b2, lo.b3, hi.b2, hi.b3]
    return __builtin_amdgcn_perm(rne_(hi), rne_(lo), 0x07060302u);
}
#endif

__device__ __forceinline__ int ldf(const int* p) {
    return __hip_atomic_load(p, __ATOMIC_RELAXED, __HIP_MEMORY_SCOPE_WORKGROUP);
}
__device__ __forceinline__ void stf(int* p, int v) {
    __hip_atomic_store(p, v, __ATOMIC_RELAXED, __HIP_MEMORY_SCOPE_WORKGROUP);
}

// One block per batch (128 blocks). Wave 0 = consumer: the sequential
// recurrence entirely in MFMA C/D register space. Waves 1..7 = producers:
// load x_t from global in kappa-gather order (per (c,j): two contiguous 128B
// segments -> coalesced), add b, pack bf16, deposit A-frags in a 32-slot ring.
//
// Recurrence (transposed space, u = h^T + b2^T):
//   u_{t+1} = (b+x_t)^T @ bf16(u_t) + b2^T   via MFMA C-operand = b2^T.
// C/D layout: col=lane&31, row=(reg&3)+8*(reg>>2)+4*(lane>>5).
// kappa(c,h,j)=c*16+4h+(j&3)+8*(j>>2) makes the B fragment equal the natural
// C/D register order -> recurrent state never crosses lanes.
// [Layout + numerics verified: absmax 2.44e-4.]
//
// SESSION ROOFLINE NOTE (round-4 analysis): dur_us for this problem is
// ~320 us of harness workspace-poison fills (2 x 1 GiB fillBufferAligned at
// ~6.6 TB/s, visible in rocprof) + ~44 us of this kernel. The kernel's 44 us
// is ~97% of the mandatory-traffic floor: x = 268 MB f32 read at ~6.1 TB/s
// (achievable peak 6.3). The chunked affine-scan variant (round 4) verified
// correct but cost +10 us (extra launch + stage2) -> reverted to this.
//
// Sync: flags[s] == t+1 publishes slot t (exact sequence values, no ABA);
// relaxed atomics + __threadfence_block() for order; ring reads/writes are
// PLAIN accesses so they vectorize/pipeline (volatile ring reads serialized
// 8 ds_reads -> ~1100 cyc/step in an earlier session round).
__global__ void __launch_bounds__(64 * (NP + 1), 1)
minrnn_kernel(const float* __restrict__ x, const float* __restrict__ bvec,
              const float* __restrict__ b2vec, const float* __restrict__ h0,
              float* __restrict__ out)
{
    __shared__ unsigned ring[S * 512];   // 64 KB, slot base (t%S)*512, elem d*64+l
    __shared__ int flags[S];
    __shared__ int consumed;             // iterations <= consumed fully done

    const int tid  = threadIdx.x;
    const int wave = tid >> 6;
    const int l    = tid & 63;
    const int col  = l & 31;
    const int half = l >> 5;
    const int bb   = blockIdx.x;

    if (tid < S) flags[tid] = 0;
    if (tid == 0) consumed = -1;
    __syncthreads();

    if (wave == 0) {
        // ---------------- consumer ----------------
        float u[16];
        f32x16 cb2;
#pragma unroll
        for (int i = 0; i < 16; ++i) {
            const int row = (i & 3) + 8 * (i >> 2) + 4 * half;
            const float b2v = b2vec[col * 32 + row];
            cb2[i] = b2v;
            u[i] = h0[bb * 1024 + col * 32 + row] + b2v;
        }

        // prologue: wait slot 0, read into cur, prefetch flag 1
        int flagn = ldf(&flags[0]);
        while (flagn != 1) flagn = ldf(&flags[0]);
        __threadfence_block();
        unsigned cur[8], nxt[8];
#pragma unroll
        for (int d = 0; d < 8; ++d) cur[d] = ring[d * 64 + l];
        flagn = ldf(&flags[1]);

        for (int t = 0; t < TSTEPS; ++t) {
            if (t < TSTEPS - 1) {
                const int want = t + 2;           // flag value for slot t+1
                while (flagn != want) flagn = ldf(&flags[(t + 1) & (S - 1)]);
                __threadfence_block();            // acquire: order ring reads after flag
                const int sb = ((t + 1) & (S - 1)) << 9;
#pragma unroll
                for (int d = 0; d < 8; ++d) nxt[d] = ring[sb + d * 64 + l];
                if (t + 2 < TSTEPS) flagn = ldf(&flags[(t + 2) & (S - 1)]);
            }

            // B operand: bf16(u) in natural register order == kappa frag order
            unsigned pb[8];
#pragma unroll
            for (int i = 0; i < 8; ++i) pb[i] = packbf(u[2 * i], u[2 * i + 1]);
            const bf16x8 B0 = __builtin_bit_cast(bf16x8, (uint4v){pb[0], pb[1], pb[2], pb[3]});
            const bf16x8 B1 = __builtin_bit_cast(bf16x8, (uint4v){pb[4], pb[5], pb[6], pb[7]});
            const bf16x8 A0 = __builtin_bit_cast(bf16x8, (uint4v){cur[0], cur[1], cur[2], cur[3]});
            const bf16x8 A1 = __builtin_bit_cast(bf16x8, (uint4v){cur[4], cur[5], cur[6], cur[7]});

            f32x16 acc = __builtin_amdgcn_mfma_f32_32x32x16_bf16(A0, B0, cb2, 0, 0, 0);
            acc        = __builtin_amdgcn_mfma_f32_32x32x16_bf16(A1, B1, acc, 0, 0, 0);
#pragma unroll
            for (int i = 0; i < 16; ++i) u[i] = acc[i];

            if (l == 0 && (t & 7) == 7) stf(&consumed, t);
#pragma unroll
            for (int d = 0; d < 8; ++d) cur[d] = nxt[d];
        }

        // out = u - b2^T = g^T : lane holds g[row][col] -> out[col*32+row]
#pragma unroll
        for (int i = 0; i < 16; ++i) {
            const int row = (i & 3) + 8 * (i >> 2) + 4 * half;
            out[bb * 1024 + col * 32 + row] = u[i] - cb2[i];
        }
    } else {
        // ---------------- producers ----------------
        const int p = wave - 1;
        float bA[16];
        int off[16];
#pragma unroll
        for (int c = 0; c < 2; ++c)
#pragma unroll
            for (int j = 0; j < 8; ++j) {
                const int k = c * 16 + half * 4 + (j & 3) + 8 * (j >> 2); // kappa
                bA[c * 8 + j] = bvec[k * 32 + col];
                off[c * 8 + j] = c * 512 + half * 128 + (j >> 2) * 256 + (j & 3) * 32 + col;
            }
        const float* xb = x + (size_t)bb * TSTEPS * 1024;

        auto emit = [&](int t, const float* v) {
            // ring space + flag-slot reuse guard (see sequence-number analysis)
            while (ldf(&consumed) < t - 33) {}
            unsigned pa[8];
#pragma unroll
            for (int i = 0; i < 8; ++i)
                pa[i] = packbf(v[2 * i] + bA[2 * i], v[2 * i + 1] + bA[2 * i + 1]);
            const int sb = (t & (S - 1)) << 9;
#pragma unroll
            for (int d = 0; d < 8; ++d) ring[sb + d * 64 + l] = pa[d];
            __threadfence_block();               // release: data before flag
            if (l == 0) stf(&flags[t & (S - 1)], t + 1);
        };

        // 2-batch software pipeline; sched_barrier pins load issue (earlier
        // session: RA sank prefetch loads to use site, killing the pipeline).
        for (int t = p; t < TSTEPS; t += 2 * NP) {
            const int t2 = t + NP;
            float va[16], vb[16];
#pragma unroll
            for (int i = 0; i < 16; ++i) va[i] = xb[t * 1024 + off[i]];
            if (t2 < TSTEPS) {
#pragma unroll
                for (int i = 0; i < 16; ++i) vb[i] = xb[t2 * 1024 + off[i]];
            }
            __builtin_amdgcn_sched_barrier(0);
            emit(t, va);
            if (t2 < TSTEPS) emit(t2, vb);
        }
    }
}

extern "C" void kernel_launch(void* const* d_in, const int* in_sizes, int n_in,
                              void* d_out, int out_size, void* d_ws, size_t ws_size,
                              hipStream_t stream)
{
    const float* x  = (const float*)d_in[0];
    const float* b  = (const float*)d_in[1];
    const float* b2 = (const float*)d_in[2];
    const float* h0 = (const float*)d_in[3];
    float* out = (float*)d_out;
    minrnn_kernel<<<128, 64 * (NP + 1), 0, stream>>>(x, b, b2, h0, out);
}